// Round 4
// baseline (508.054 us; speedup 1.0000x reference)
//
#include <hip/hip_runtime.h>
#include <cstdint>
#include <cstddef>

// ---------------------------------------------------------------------------
// CrossAttention2D: out = softmax((rope(XqWq^T) rope(XkWk^T)^T)/8) (XvWv^T) Wo^T
// B=4, N=48*48=2304, E=1024, H=16, D=64. bf16 MFMA, fp32 accum.
// R9: cvt_pkrtz REVERTED (R8: +25us pure stall, same VALU busy time —
//     confirms m240 "don't hand-write cvt_pk"). attn restructured to 8-wave
//     512-thread blocks, TQ=256: same per-wave work (32 q-rows), same 48KB
//     LDS now shared by 8 waves, grid 1152->576 blocks (~1.1 occupancy
//     rounds), staging 2 loads/wave/tile (steady-state s_waitcnt vmcnt(2)).
//     GEMMs stay at the R5 single-buffer structure (283us verified).
// ---------------------------------------------------------------------------

typedef __bf16 bf16x8 __attribute__((ext_vector_type(8)));
typedef __bf16 bf16x4 __attribute__((ext_vector_type(4)));
typedef _Float16 f16x4 __attribute__((ext_vector_type(4)));
typedef _Float16 f16x8 __attribute__((ext_vector_type(8)));
typedef float f32x4 __attribute__((ext_vector_type(4)));

constexpr int Bc = 4, Hc = 16, Nc = 2304, Ec = 1024, WPc = 48;
constexpr int BNc = Bc * Nc;  // 9216

__device__ __forceinline__ f32x4 mfma16(bf16x8 a, bf16x8 b, f32x4 c) {
  return __builtin_amdgcn_mfma_f32_16x16x32_bf16(a, b, c, 0, 0, 0);
}
__device__ __forceinline__ f32x4 mfmah32(f16x8 a, f16x8 b, f32x4 c) {
  return __builtin_amdgcn_mfma_f32_16x16x32_f16(a, b, c, 0, 0, 0);
}

#define GPTR(p) ((const __attribute__((address_space(1))) void*)(p))
#define LPTR(p) ((__attribute__((address_space(3))) void*)(p))

// --------------------------- fp32 -> bf16 convert ---------------------------
__global__ __launch_bounds__(256) void cvt_bf16(const float* __restrict__ s,
                                                __bf16* __restrict__ d, int n) {
  int i = (blockIdx.x * 256 + threadIdx.x) * 8;
  if (i >= n) return;
  float4 f0 = *(const float4*)(s + i);
  float4 f1 = *(const float4*)(s + i + 4);
  bf16x8 v;
  v[0] = (__bf16)f0.x; v[1] = (__bf16)f0.y; v[2] = (__bf16)f0.z; v[3] = (__bf16)f0.w;
  v[4] = (__bf16)f1.x; v[5] = (__bf16)f1.y; v[6] = (__bf16)f1.z; v[7] = (__bf16)f1.w;
  *(bf16x8*)(d + i) = v;
}

// ---------------- shared GEMM core: 128x128 tile, BK=32, 4 waves ------------
// R5 structure: single LDS buffer, global_load_lds staging, 2 barriers/K-step.
#define GEMM_CORE(APTR, WPTR, KDIM)                                             \
  __shared__ __align__(16) __bf16 As[128 * 32];                                 \
  __shared__ __align__(16) __bf16 Bs[128 * 32];                                 \
  const int t = threadIdx.x;                                                    \
  const int lane = t & 63, wave = t >> 6;                                       \
  const int wm = wave & 1, wn = wave >> 1;                                      \
  const int quad = lane >> 4, l15 = lane & 15;                                  \
  const int rowInC = lane >> 2, colC = (lane & 3) * 8;                          \
  const __bf16* Ab = (APTR) + (size_t)(tm * 128) * (KDIM);                      \
  const __bf16* Wb = (WPTR) + (size_t)(tn * 128) * (KDIM);                      \
  f32x4 zero = {0.f, 0.f, 0.f, 0.f};                                            \
  f32x4 acc[4][4];                                                              \
  for (int i = 0; i < 4; ++i)                                                   \
    for (int j = 0; j < 4; ++j) acc[i][j] = zero;                               \
  for (int kk = 0; kk < (KDIM); kk += 32) {                                     \
    _Pragma("unroll") for (int tch = 0; tch < 2; ++tch) {                       \
      const int ch = wave * 2 + tch;                                            \
      const int row = ch * 16 + rowInC;                                         \
      __builtin_amdgcn_global_load_lds(GPTR(Ab + (size_t)row * (KDIM) + kk + colC), \
                                       LPTR(As + ch * 512), 16, 0, 0);          \
      __builtin_amdgcn_global_load_lds(GPTR(Wb + (size_t)row * (KDIM) + kk + colC), \
                                       LPTR(Bs + ch * 512), 16, 0, 0);          \
    }                                                                           \
    __syncthreads();                                                            \
    bf16x8 af[4], bfg[4];                                                       \
    _Pragma("unroll") for (int i = 0; i < 4; ++i)                               \
        af[i] = *(const bf16x8*)(As + (wm * 64 + i * 16 + l15) * 32 + quad * 8);\
    _Pragma("unroll") for (int j = 0; j < 4; ++j)                               \
        bfg[j] = *(const bf16x8*)(Bs + (wn * 64 + j * 16 + l15) * 32 + quad * 8);\
    _Pragma("unroll") for (int i = 0; i < 4; ++i)                               \
      _Pragma("unroll") for (int j = 0; j < 4; ++j)                             \
        acc[i][j] = mfma16(af[i], bfg[j], acc[i][j]);                           \
    __syncthreads();                                                            \
  }                                                                             \
  const int m0 = tm * 128 + wm * 64;                                            \
  const int nb0 = tn * 128 + wn * 64;

// ---------------- GEMM 1: fused Q+K projection + RoPE + head pack -----------
// Col tiles 0..7 -> Q (natural order); 8..15 -> K. K rows get BOTH the 16B
// d-chunk XOR swizzle (by stored-position low bits) AND the token
// bit-permutation within each 64-block: t64=[hi q1 q0 c r1 r0] is stored at
// position p=[hi c q1 q0 r1 r0], so QK^T's C-regs line up with the k-slots
// (k = quad*8+j) of the 16x16x32 PV B-fragment with zero cross-lane traffic.
__global__ __launch_bounds__(256) void gemm_qk(const __bf16* __restrict__ qkb,
                                               const __bf16* __restrict__ Wqk,
                                               const float* __restrict__ bq,
                                               const float* __restrict__ bk,
                                               __bf16* __restrict__ Qhp,
                                               __bf16* __restrict__ Khp,
                                               float qscale) {
  const int tn = blockIdx.x & 15;   // 16 col tiles over 2048
  const int tm = blockIdx.x >> 4;   // 72 row tiles
  const int proj = tn >> 3;         // 0 = Q, 1 = K (block-uniform)
  const __bf16* Asel = qkb + (size_t)proj * BNc * Ec;
  GEMM_CORE(Asel, Wqk, Ec)

  const int h = (nb0 >> 6) & 15;
  const float scale = proj ? 1.0f : qscale;
  __bf16* O = proj ? Khp : Qhp;
  const float* bb = proj ? bk : bq;
  float bj[4];
#pragma unroll
  for (int j = 0; j < 4; ++j) bj[j] = bb[(nb0 + j * 16 + l15) & 1023];
  const float f = exp2f(-(float)l15 * 0.8304820237218406f);
  const int lo3 = l15 & 7, hi8 = l15 >> 3;
#pragma unroll
  for (int i = 0; i < 4; ++i) {
#pragma unroll
    for (int r = 0; r < 4; ++r) {
      const int m = m0 + i * 16 + quad * 4 + r;
      const int b = m / Nc;
      const int ntok = m - b * Nc;
      const int ph = ntok / WPc, pw = ntok - (ntok / WPc) * WPc;
      float sh, ch, sw, cw;
      __sincosf((float)ph * f, &sh, &ch);
      __sincosf((float)pw * f, &sw, &cw);
      const float x0 = acc[i][0][r] + bj[0];
      const float x1 = acc[i][1][r] + bj[1];
      const float x2 = acc[i][2][r] + bj[2];
      const float x3 = acc[i][3][r] + bj[3];
      int wtok = ntok;
      if (proj) {
        const int t64 = ntok & 63;
        wtok = (ntok & ~63) | (t64 & 35) | ((t64 & 4) << 2) | ((t64 & 24) >> 1);
      }
      __bf16* Op = O + ((size_t)(b * Hc + h) * Nc + wtok) * 64;
      const int n7 = proj ? (wtok & 7) : 0;
      Op[(((0 + hi8) ^ n7) << 3) | lo3] = (__bf16)((x0 * ch - x1 * sh) * scale);
      Op[(((2 + hi8) ^ n7) << 3) | lo3] = (__bf16)((x1 * ch + x0 * sh) * scale);
      Op[(((4 + hi8) ^ n7) << 3) | lo3] = (__bf16)((x2 * cw - x3 * sw) * scale);
      Op[(((6 + hi8) ^ n7) << 3) | lo3] = (__bf16)((x3 * cw + x2 * sw) * scale);
    }
  }
}

// ---------------- GEMM 2: V projection -> f16 V^T (b,h,d,n) -----------------
// Tokens stay in natural order; within each 64-token block the 8-token 16B
// chunk c8 is stored at position c8 ^ (d&7) so attn's ds_read_b128 of the
// x32 A-fragment is bank-spread (same structure as the K-tile read: 0 confl).
__global__ __launch_bounds__(256) void gemm_v(const __bf16* __restrict__ A,
                                              const __bf16* __restrict__ Wv,
                                              const float* __restrict__ bv,
                                              _Float16* __restrict__ Vt) {
  const int tn = blockIdx.x & 7;
  const int tm = blockIdx.x >> 3;
  GEMM_CORE(A, Wv, Ec)

  const int h = nb0 >> 6;
#pragma unroll
  for (int i = 0; i < 4; ++i) {
    const int m = m0 + i * 16 + quad * 4;
    const int b = m / Nc;
    const int ntok = m - b * Nc;
    const int base = (ntok >> 6) * 64 + (((ntok >> 2) & 1) << 2);
    const int c8 = (ntok >> 3) & 7;
#pragma unroll
    for (int j = 0; j < 4; ++j) {
      const int d = j * 16 + l15;
      const float bi = bv[nb0 + j * 16 + l15];
      f16x4 v;
#pragma unroll
      for (int r = 0; r < 4; ++r) v[r] = (_Float16)(acc[i][j][r] + bi);
      const int off = base + ((c8 ^ (l15 & 7)) << 3);
      *(f16x4*)(Vt + ((size_t)(b * Hc + h) * 64 + d) * Nc + off) = v;
    }
  }
}

// ---------------- GEMM 3: output projection, fp32 + bias --------------------
__global__ __launch_bounds__(256) void gemm_out(const __bf16* __restrict__ A,
                                                const __bf16* __restrict__ Wo,
                                                const float* __restrict__ bo,
                                                float* __restrict__ C) {
  const int tn = blockIdx.x & 7;
  const int tm = blockIdx.x >> 3;
  GEMM_CORE(A, Wo, Ec)

#pragma unroll
  for (int j = 0; j < 4; ++j) {
    const int n = nb0 + j * 16 + l15;
    const float bi = bo[n];
#pragma unroll
    for (int i = 0; i < 4; ++i) {
      const int m = m0 + i * 16 + quad * 4;
#pragma unroll
      for (int r = 0; r < 4; ++r) C[(size_t)(m + r) * Ec + n] = acc[i][j][r] + bi;
    }
  }
}

// --------------------------- flash attention (R9) ---------------------------
// 8 waves x 32 q-rows = TQ 256. 48KB LDS (3-buffer K+V) shared by 8 waves;
// 2 global_load_lds per wave per tile; steady-state s_waitcnt vmcnt(2).
constexpr int TQ = 256, TK = 64, NT = Nc / TK;  // 9 q-tiles, 36 k-tiles

__global__ __launch_bounds__(512) void attn(const __bf16* __restrict__ Qh,
                                            const __bf16* __restrict__ Kg,
                                            const _Float16* __restrict__ Vg,
                                            __bf16* __restrict__ Om) {
  const int bh = blockIdx.x;
  const int t = threadIdx.x, wave = t >> 6, lane = t & 63;
  const int quad = lane >> 4, l15 = lane & 15;

  __shared__ __align__(16) __bf16 Kls[3][TK * 64];
  __shared__ __align__(16) _Float16 Vls[3][TK * 64];

  const int qbase = blockIdx.y * TQ + wave * 32;
  bf16x8 bq[2][2];
#pragma unroll
  for (int s = 0; s < 2; ++s)
#pragma unroll
    for (int ks = 0; ks < 2; ++ks)
      bq[s][ks] = *(const bf16x8*)(Qh + ((size_t)bh * Nc + qbase + s * 16 + l15) * 64 +
                                   ks * 32 + quad * 8);
  // Pin the Q-fragment waits HERE (before the pipeline) so the waitcnt pass
  // cannot inject a vmcnt drain inside the main loop; then zero the counter
  // baseline for the manual vmcnt bookkeeping below.
#pragma unroll
  for (int s = 0; s < 2; ++s)
#pragma unroll
    for (int ks = 0; ks < 2; ++ks) asm volatile("" : "+v"(bq[s][ks]));
  asm volatile("s_waitcnt vmcnt(0)" ::: "memory");

  const __bf16* Kbh = Kg + (size_t)bh * Nc * 64;
  const _Float16* Vbh = Vg + (size_t)bh * 64 * Nc;

  const f32x4 zero = {0.f, 0.f, 0.f, 0.f};
  f32x4 oacc[2][4] = {{zero, zero, zero, zero}, {zero, zero, zero, zero}};
  f32x4 osum[2] = {zero, zero};
  const f16x8 fones8 = {(_Float16)1.f, (_Float16)1.f, (_Float16)1.f, (_Float16)1.f,
                        (_Float16)1.f, (_Float16)1.f, (_Float16)1.f, (_Float16)1.f};

  const int vrow = lane >> 3, vcol = (lane & 7) * 8;

  // 8 waves: wave w stages K chunk w (512 elems) and V chunk w (d-rows
  // w*8..w*8+7). 2 loads/wave/tile.
#define STAGE(KT2, BUF2)                                                        \
  {                                                                             \
    __builtin_amdgcn_global_load_lds(                                           \
        GPTR(Kbh + (size_t)(KT2) * (TK * 64) + wave * 512 + lane * 8),          \
        LPTR(&Kls[BUF2][wave * 512]), 16, 0, 0);                                \
    const int dV = wave * 8 + vrow;                                             \
    __builtin_amdgcn_global_load_lds(                                           \
        GPTR(Vbh + (size_t)dV * Nc + (size_t)(KT2) * 64 + vcol),                \
        LPTR(&Vls[BUF2][wave * 512]), 16, 0, 0);                                \
  }

  // sacc C-layout: col = q (lane&15), row = K-tile position quad*4+r.
  // With the write-side token permutation, lane quad's sacc regs
  // {[2*c2][0..3],[2*c2+1][0..3]} are exactly tokens c2*32 + quad*8 + (0..7)
  // = the k-slots of the 16x16x32_f16 B-fragment. No cross-lane traffic.
#define COMPUTE(BUF)                                                            \
  {                                                                             \
    f32x4 sacc[2][4] = {{zero, zero, zero, zero}, {zero, zero, zero, zero}};    \
    __builtin_amdgcn_s_setprio(1);                                              \
    _Pragma("unroll") for (int ks = 0; ks < 2; ++ks) {                          \
      _Pragma("unroll") for (int ct = 0; ct < 4; ++ct) {                        \
        const bf16x8 ak = *(const bf16x8*)(&Kls[BUF][(ct * 16 + l15) * 64 +     \
            (((ks * 4 + quad) ^ (l15 & 7)) << 3)]);                             \
        sacc[0][ct] = mfma16(ak, bq[0][ks], sacc[0][ct]);                       \
        sacc[1][ct] = mfma16(ak, bq[1][ks], sacc[1][ct]);                       \
      }                                                                         \
    }                                                                           \
    __builtin_amdgcn_s_setprio(0);                                              \
    f16x8 pf[2][2];                                                             \
    _Pragma("unroll") for (int s = 0; s < 2; ++s)                               \
      _Pragma("unroll") for (int c2 = 0; c2 < 2; ++c2) {                        \
        _Pragma("unroll") for (int r = 0; r < 4; ++r) {                         \
          pf[s][c2][r]     = (_Float16)exp2f(sacc[s][2 * c2][r]);               \
          pf[s][c2][4 + r] = (_Float16)exp2f(sacc[s][2 * c2 + 1][r]);           \
        }                                                                       \
      }                                                                         \
    __builtin_amdgcn_s_setprio(1);                                              \
    _Pragma("unroll") for (int c2 = 0; c2 < 2; ++c2) {                          \
      _Pragma("unroll") for (int dt = 0; dt < 4; ++dt) {                        \
        const f16x8 av = *(const f16x8*)(&Vls[BUF][(dt * 16 + l15) * 64 +       \
            (((c2 * 4 + quad) ^ (l15 & 7)) << 3)]);                             \
        oacc[0][dt] = mfmah32(av, pf[0][c2], oacc[0][dt]);                      \
        oacc[1][dt] = mfmah32(av, pf[1][c2], oacc[1][dt]);                      \
      }                                                                         \
      osum[0] = mfmah32(fones8, pf[0][c2], osum[0]);                            \
      osum[1] = mfmah32(fones8, pf[1][c2], osum[1]);                            \
    }                                                                           \
    __builtin_amdgcn_s_setprio(0);                                              \
  }

  // One barrier per K-tile. Steady state: tile kt's 2 loads retired, tile
  // kt+1's 2 in flight -> s_waitcnt vmcnt(2). Stage is AFTER the barrier:
  // buffer (kt+2)%3 was last read in COMPUTE(kt-1), finished by all waves.
#define PHASE(KT, BUF, WN, DS)                                                  \
  asm volatile("s_waitcnt vmcnt(" #WN ")" ::: "memory");                        \
  __builtin_amdgcn_s_barrier();                                                 \
  asm volatile("" ::: "memory");                                                \
  if (DS) STAGE((KT) + 2, ((BUF) + 2) % 3)                                      \
  COMPUTE(BUF)

  STAGE(0, 0)
  STAGE(1, 1)

#pragma unroll 1
  for (int kt = 0; kt < NT - 3; kt += 3) {
    PHASE(kt, 0, 2, 1)
    PHASE(kt + 1, 1, 2, 1)
    PHASE(kt + 2, 2, 2, 1)
  }
  PHASE(NT - 3, 0, 2, 1)   // stages tile NT-1
  PHASE(NT - 2, 1, 2, 0)
  PHASE(NT - 1, 2, 0, 0)

  // ---- epilogue: rinv from ones-MFMA (all regs equal), normalize, store ----
  const int b = bh >> 4, h = bh & 15;
#pragma unroll
  for (int s = 0; s < 2; ++s) {
    const float rinv = 1.0f / osum[s][0];
    __bf16* Op = Om + ((size_t)b * Nc + qbase + s * 16 + l15) * Ec + h * 64 + quad * 4;
#pragma unroll
    for (int dt = 0; dt < 4; ++dt) {
      bf16x4 o;
#pragma unroll
      for (int r = 0; r < 4; ++r) o[r] = (__bf16)(oacc[s][dt][r] * rinv);
      *(bf16x4*)(Op + dt * 16) = o;
    }
  }
#undef STAGE
#undef COMPUTE
#undef PHASE
}

// ---------------------------------------------------------------------------
extern "C" void kernel_launch(void* const* d_in, const int* in_sizes, int n_in,
                              void* d_out, int out_size, void* d_ws, size_t ws_size,
                              hipStream_t stream) {
  const float* q  = (const float*)d_in[0];
  const float* k  = (const float*)d_in[1];
  const float* v  = (const float*)d_in[2];
  const float* Wq = (const float*)d_in[3];
  const float* bq = (const float*)d_in[4];
  const float* Wk = (const float*)d_in[5];
  const float* bk = (const float*)d_in[6];
  const float* Wv = (const float*)d_in[7];
  const float* bv = (const float*)d_in[8];
  const float* Wo = (const float*)d_in[9];
  const float* bo = (const float*)d_in[10];
  float* out = (float*)d_out;

  const size_t EE = (size_t)Ec * Ec;          // 1 M elems
  const size_t BNE = (size_t)BNc * Ec;        // 9.4 M elems

  // workspace carve (~102 MB with aliasing). qb and kb MUST be adjacent:
  // gemm_qk indexes A as qb + proj*BNE.
  char* w = (char*)d_ws;
  __bf16* Wqkb = (__bf16*)w; w += 2 * EE * 2;  // W_q rows | W_k rows (2048x1024)
  __bf16* Wvb  = (__bf16*)w; w += EE * 2;
  __bf16* Wob  = (__bf16*)w; w += EE * 2;
  __bf16* qb   = (__bf16*)w; w += BNE * 2;
  __bf16* kb   = (__bf16*)w; w += BNE * 2;    // == qb + BNE
  __bf16* vb   = (__bf16*)w; w += BNE * 2;
  __bf16* Qhp  = (__bf16*)w; w += BNE * 2;
  __bf16* Khp  = (__bf16*)w; w += BNE * 2;    // token-permuted + d-swizzled
  _Float16* Vtp = (_Float16*)kb;  // kb dead after gemm_qk; gemm_v writes here
  __bf16* Omp = qb;               // qb dead after gemm_qk; attn writes here

  const dim3 blk(256);
  const dim3 blkA(512);
  const dim3 gCvtW(EE / 8 / 256);     // 512
  const dim3 gCvtA(BNE / 8 / 256);    // 4608
  const dim3 gQK(16 * (BNc / 128));   // 1152
  const dim3 gG(8 * (BNc / 128));     // 576
  const dim3 gAttn(Bc * Hc, Nc / TQ); // (64, 9)

  cvt_bf16<<<gCvtW, blk, 0, stream>>>(Wq, Wqkb, (int)EE);
  cvt_bf16<<<gCvtW, blk, 0, stream>>>(Wk, Wqkb + EE, (int)EE);
  cvt_bf16<<<gCvtW, blk, 0, stream>>>(Wv, Wvb, (int)EE);
  cvt_bf16<<<gCvtW, blk, 0, stream>>>(Wo, Wob, (int)EE);
  cvt_bf16<<<gCvtA, blk, 0, stream>>>(q, qb, (int)BNE);
  cvt_bf16<<<gCvtA, blk, 0, stream>>>(k, kb, (int)BNE);
  cvt_bf16<<<gCvtA, blk, 0, stream>>>(v, vb, (int)BNE);

  const float qscale = 0.125f * 1.44269504088896340736f;  // 1/sqrt(64) * log2(e)

  gemm_qk<<<gQK, blk, 0, stream>>>(qb, Wqkb, bq, bk, Qhp, Khp, qscale);
  gemm_v<<<gG, blk, 0, stream>>>(vb, Wvb, bv, Vtp);
  attn<<<gAttn, blkA, 0, stream>>>(Qhp, Khp, Vtp, Omp);
  gemm_out<<<gG, blk, 0, stream>>>(Omp, Wob, bo, out);
}

// Round 6
// 484.720 us; speedup vs baseline: 1.0481x; 1.0481x over previous
//
#include <hip/hip_runtime.h>
#include <cstdint>
#include <cstddef>

// ---------------------------------------------------------------------------
// CrossAttention2D: out = softmax((rope(XqWq^T) rope(XkWk^T)^T)/8) (XvWv^T) Wo^T
// B=4, N=48*48=2304, E=1024, H=16, D=64. bf16 MFMA, fp32 accum.
// R10 (resubmit; round-5 bench was an infra failure, kernel never ran):
//     attn back to the R6 4-wave/TQ=128 structure (R9's 8-wave blocks cut
//     block diversity at unchanged LDS: -17us). New: V double-buffered
//     (K stays triple-buffered) -> 40KB LDS = exactly 4 blocks/CU (was 3 at
//     48KB). V is staged 1 tile ahead (legal: its dest buffer was last read
//     in COMPUTE(kt-1), finished before this phase's barrier); V issued
//     BEFORE K each phase so steady-state s_waitcnt vmcnt(2) drains
//     {K(kt),V(kt)} while K(kt+1) stays in flight. GEMMs: R5 single-buffer
//     (283us verified).
// ---------------------------------------------------------------------------

typedef __bf16 bf16x8 __attribute__((ext_vector_type(8)));
typedef __bf16 bf16x4 __attribute__((ext_vector_type(4)));
typedef _Float16 f16x4 __attribute__((ext_vector_type(4)));
typedef _Float16 f16x8 __attribute__((ext_vector_type(8)));
typedef float f32x4 __attribute__((ext_vector_type(4)));

constexpr int Bc = 4, Hc = 16, Nc = 2304, Ec = 1024, WPc = 48;
constexpr int BNc = Bc * Nc;  // 9216

__device__ __forceinline__ f32x4 mfma16(bf16x8 a, bf16x8 b, f32x4 c) {
  return __builtin_amdgcn_mfma_f32_16x16x32_bf16(a, b, c, 0, 0, 0);
}
__device__ __forceinline__ f32x4 mfmah32(f16x8 a, f16x8 b, f32x4 c) {
  return __builtin_amdgcn_mfma_f32_16x16x32_f16(a, b, c, 0, 0, 0);
}

#define GPTR(p) ((const __attribute__((address_space(1))) void*)(p))
#define LPTR(p) ((__attribute__((address_space(3))) void*)(p))

// --------------------------- fp32 -> bf16 convert ---------------------------
__global__ __launch_bounds__(256) void cvt_bf16(const float* __restrict__ s,
                                                __bf16* __restrict__ d, int n) {
  int i = (blockIdx.x * 256 + threadIdx.x) * 8;
  if (i >= n) return;
  float4 f0 = *(const float4*)(s + i);
  float4 f1 = *(const float4*)(s + i + 4);
  bf16x8 v;
  v[0] = (__bf16)f0.x; v[1] = (__bf16)f0.y; v[2] = (__bf16)f0.z; v[3] = (__bf16)f0.w;
  v[4] = (__bf16)f1.x; v[5] = (__bf16)f1.y; v[6] = (__bf16)f1.z; v[7] = (__bf16)f1.w;
  *(bf16x8*)(d + i) = v;
}

// ---------------- shared GEMM core: 128x128 tile, BK=32, 4 waves ------------
// R5 structure: single LDS buffer, global_load_lds staging, 2 barriers/K-step.
#define GEMM_CORE(APTR, WPTR, KDIM)                                             \
  __shared__ __align__(16) __bf16 As[128 * 32];                                 \
  __shared__ __align__(16) __bf16 Bs[128 * 32];                                 \
  const int t = threadIdx.x;                                                    \
  const int lane = t & 63, wave = t >> 6;                                       \
  const int wm = wave & 1, wn = wave >> 1;                                      \
  const int quad = lane >> 4, l15 = lane & 15;                                  \
  const int rowInC = lane >> 2, colC = (lane & 3) * 8;                          \
  const __bf16* Ab = (APTR) + (size_t)(tm * 128) * (KDIM);                      \
  const __bf16* Wb = (WPTR) + (size_t)(tn * 128) * (KDIM);                      \
  f32x4 zero = {0.f, 0.f, 0.f, 0.f};                                            \
  f32x4 acc[4][4];                                                              \
  for (int i = 0; i < 4; ++i)                                                   \
    for (int j = 0; j < 4; ++j) acc[i][j] = zero;                               \
  for (int kk = 0; kk < (KDIM); kk += 32) {                                     \
    _Pragma("unroll") for (int tch = 0; tch < 2; ++tch) {                       \
      const int ch = wave * 2 + tch;                                            \
      const int row = ch * 16 + rowInC;                                         \
      __builtin_amdgcn_global_load_lds(GPTR(Ab + (size_t)row * (KDIM) + kk + colC), \
                                       LPTR(As + ch * 512), 16, 0, 0);          \
      __builtin_amdgcn_global_load_lds(GPTR(Wb + (size_t)row * (KDIM) + kk + colC), \
                                       LPTR(Bs + ch * 512), 16, 0, 0);          \
    }                                                                           \
    __syncthreads();                                                            \
    bf16x8 af[4], bfg[4];                                                       \
    _Pragma("unroll") for (int i = 0; i < 4; ++i)                               \
        af[i] = *(const bf16x8*)(As + (wm * 64 + i * 16 + l15) * 32 + quad * 8);\
    _Pragma("unroll") for (int j = 0; j < 4; ++j)                               \
        bfg[j] = *(const bf16x8*)(Bs + (wn * 64 + j * 16 + l15) * 32 + quad * 8);\
    _Pragma("unroll") for (int i = 0; i < 4; ++i)                               \
      _Pragma("unroll") for (int j = 0; j < 4; ++j)                             \
        acc[i][j] = mfma16(af[i], bfg[j], acc[i][j]);                           \
    __syncthreads();                                                            \
  }                                                                             \
  const int m0 = tm * 128 + wm * 64;                                            \
  const int nb0 = tn * 128 + wn * 64;

// ---------------- GEMM 1: fused Q+K projection + RoPE + head pack -----------
// Col tiles 0..7 -> Q (natural order); 8..15 -> K. K rows get BOTH the 16B
// d-chunk XOR swizzle (by stored-position low bits) AND the token
// bit-permutation within each 64-block: t64=[hi q1 q0 c r1 r0] is stored at
// position p=[hi c q1 q0 r1 r0], so QK^T's C-regs line up with the k-slots
// (k = quad*8+j) of the 16x16x32 PV B-fragment with zero cross-lane traffic.
__global__ __launch_bounds__(256) void gemm_qk(const __bf16* __restrict__ qkb,
                                               const __bf16* __restrict__ Wqk,
                                               const float* __restrict__ bq,
                                               const float* __restrict__ bk,
                                               __bf16* __restrict__ Qhp,
                                               __bf16* __restrict__ Khp,
                                               float qscale) {
  const int tn = blockIdx.x & 15;   // 16 col tiles over 2048
  const int tm = blockIdx.x >> 4;   // 72 row tiles
  const int proj = tn >> 3;         // 0 = Q, 1 = K (block-uniform)
  const __bf16* Asel = qkb + (size_t)proj * BNc * Ec;
  GEMM_CORE(Asel, Wqk, Ec)

  const int h = (nb0 >> 6) & 15;
  const float scale = proj ? 1.0f : qscale;
  __bf16* O = proj ? Khp : Qhp;
  const float* bb = proj ? bk : bq;
  float bj[4];
#pragma unroll
  for (int j = 0; j < 4; ++j) bj[j] = bb[(nb0 + j * 16 + l15) & 1023];
  const float f = exp2f(-(float)l15 * 0.8304820237218406f);
  const int lo3 = l15 & 7, hi8 = l15 >> 3;
#pragma unroll
  for (int i = 0; i < 4; ++i) {
#pragma unroll
    for (int r = 0; r < 4; ++r) {
      const int m = m0 + i * 16 + quad * 4 + r;
      const int b = m / Nc;
      const int ntok = m - b * Nc;
      const int ph = ntok / WPc, pw = ntok - (ntok / WPc) * WPc;
      float sh, ch, sw, cw;
      __sincosf((float)ph * f, &sh, &ch);
      __sincosf((float)pw * f, &sw, &cw);
      const float x0 = acc[i][0][r] + bj[0];
      const float x1 = acc[i][1][r] + bj[1];
      const float x2 = acc[i][2][r] + bj[2];
      const float x3 = acc[i][3][r] + bj[3];
      int wtok = ntok;
      if (proj) {
        const int t64 = ntok & 63;
        wtok = (ntok & ~63) | (t64 & 35) | ((t64 & 4) << 2) | ((t64 & 24) >> 1);
      }
      __bf16* Op = O + ((size_t)(b * Hc + h) * Nc + wtok) * 64;
      const int n7 = proj ? (wtok & 7) : 0;
      Op[(((0 + hi8) ^ n7) << 3) | lo3] = (__bf16)((x0 * ch - x1 * sh) * scale);
      Op[(((2 + hi8) ^ n7) << 3) | lo3] = (__bf16)((x1 * ch + x0 * sh) * scale);
      Op[(((4 + hi8) ^ n7) << 3) | lo3] = (__bf16)((x2 * cw - x3 * sw) * scale);
      Op[(((6 + hi8) ^ n7) << 3) | lo3] = (__bf16)((x3 * cw + x2 * sw) * scale);
    }
  }
}

// ---------------- GEMM 2: V projection -> f16 V^T (b,h,d,n) -----------------
// Tokens stay in natural order; within each 64-token block the 8-token 16B
// chunk c8 is stored at position c8 ^ (d&7) so attn's ds_read_b128 of the
// x32 A-fragment is bank-spread (same structure as the K-tile read: 0 confl).
__global__ __launch_bounds__(256) void gemm_v(const __bf16* __restrict__ A,
                                              const __bf16* __restrict__ Wv,
                                              const float* __restrict__ bv,
                                              _Float16* __restrict__ Vt) {
  const int tn = blockIdx.x & 7;
  const int tm = blockIdx.x >> 3;
  GEMM_CORE(A, Wv, Ec)

  const int h = nb0 >> 6;
#pragma unroll
  for (int i = 0; i < 4; ++i) {
    const int m = m0 + i * 16 + quad * 4;
    const int b = m / Nc;
    const int ntok = m - b * Nc;
    const int base = (ntok >> 6) * 64 + (((ntok >> 2) & 1) << 2);
    const int c8 = (ntok >> 3) & 7;
#pragma unroll
    for (int j = 0; j < 4; ++j) {
      const int d = j * 16 + l15;
      const float bi = bv[nb0 + j * 16 + l15];
      f16x4 v;
#pragma unroll
      for (int r = 0; r < 4; ++r) v[r] = (_Float16)(acc[i][j][r] + bi);
      const int off = base + ((c8 ^ (l15 & 7)) << 3);
      *(f16x4*)(Vt + ((size_t)(b * Hc + h) * 64 + d) * Nc + off) = v;
    }
  }
}

// ---------------- GEMM 3: output projection, fp32 + bias --------------------
__global__ __launch_bounds__(256) void gemm_out(const __bf16* __restrict__ A,
                                                const __bf16* __restrict__ Wo,
                                                const float* __restrict__ bo,
                                                float* __restrict__ C) {
  const int tn = blockIdx.x & 7;
  const int tm = blockIdx.x >> 3;
  GEMM_CORE(A, Wo, Ec)

#pragma unroll
  for (int j = 0; j < 4; ++j) {
    const int n = nb0 + j * 16 + l15;
    const float bi = bo[n];
#pragma unroll
    for (int i = 0; i < 4; ++i) {
      const int m = m0 + i * 16 + quad * 4;
#pragma unroll
      for (int r = 0; r < 4; ++r) C[(size_t)(m + r) * Ec + n] = acc[i][j][r] + bi;
    }
  }
}

// --------------------------- flash attention (R10) --------------------------
// 4 waves x 32 q-rows = TQ 128. K triple-buffered (2-tile prefetch), V
// double-buffered (1-tile prefetch) -> 40KB LDS = 4 blocks/CU. V issued
// before K each phase; steady-state s_waitcnt vmcnt(2).
constexpr int TQ = 128, TK = 64, NT = Nc / TK;  // 18 q-tiles, 36 k-tiles

__global__ __launch_bounds__(256) void attn(const __bf16* __restrict__ Qh,
                                            const __bf16* __restrict__ Kg,
                                            const _Float16* __restrict__ Vg,
                                            __bf16* __restrict__ Om) {
  const int bh = blockIdx.x;
  const int t = threadIdx.x, wave = t >> 6, lane = t & 63;
  const int quad = lane >> 4, l15 = lane & 15;

  __shared__ __align__(16) __bf16 Kls[3][TK * 64];   // 24 KB
  __shared__ __align__(16) _Float16 Vls[2][TK * 64]; // 16 KB

  const int qbase = blockIdx.y * TQ + wave * 32;
  bf16x8 bq[2][2];
#pragma unroll
  for (int s = 0; s < 2; ++s)
#pragma unroll
    for (int ks = 0; ks < 2; ++ks)
      bq[s][ks] = *(const bf16x8*)(Qh + ((size_t)bh * Nc + qbase + s * 16 + l15) * 64 +
                                   ks * 32 + quad * 8);
  // Pin the Q-fragment waits HERE (before the pipeline) so the waitcnt pass
  // cannot inject a vmcnt drain inside the main loop; then zero the counter
  // baseline for the manual vmcnt bookkeeping below.
#pragma unroll
  for (int s = 0; s < 2; ++s)
#pragma unroll
    for (int ks = 0; ks < 2; ++ks) asm volatile("" : "+v"(bq[s][ks]));
  asm volatile("s_waitcnt vmcnt(0)" ::: "memory");

  const __bf16* Kbh = Kg + (size_t)bh * Nc * 64;
  const _Float16* Vbh = Vg + (size_t)bh * 64 * Nc;

  const f32x4 zero = {0.f, 0.f, 0.f, 0.f};
  f32x4 oacc[2][4] = {{zero, zero, zero, zero}, {zero, zero, zero, zero}};
  f32x4 osum[2] = {zero, zero};
  const f16x8 fones8 = {(_Float16)1.f, (_Float16)1.f, (_Float16)1.f, (_Float16)1.f,
                        (_Float16)1.f, (_Float16)1.f, (_Float16)1.f, (_Float16)1.f};

  const int vrow = lane >> 3, vcol = (lane & 7) * 8;

#define STAGE_K(KT2, BUF2)                                                      \
  {                                                                             \
    _Pragma("unroll") for (int i = 0; i < 2; ++i) {                             \
      const int ch = wave * 2 + i;                                              \
      __builtin_amdgcn_global_load_lds(                                         \
          GPTR(Kbh + (size_t)(KT2) * (TK * 64) + ch * 512 + lane * 8),          \
          LPTR(&Kls[BUF2][ch * 512]), 16, 0, 0);                                \
    }                                                                           \
  }
#define STAGE_V(KT2, BUF2)                                                      \
  {                                                                             \
    _Pragma("unroll") for (int i = 0; i < 2; ++i) {                             \
      const int ch = wave * 2 + i;                                              \
      const int d = ch * 8 + vrow;                                              \
      __builtin_amdgcn_global_load_lds(                                         \
          GPTR(Vbh + (size_t)d * Nc + (size_t)(KT2) * 64 + vcol),               \
          LPTR(&Vls[BUF2][ch * 512]), 16, 0, 0);                                \
    }                                                                           \
  }

  // sacc C-layout: col = q (lane&15), row = K-tile position quad*4+r.
  // With the write-side token permutation, lane quad's sacc regs
  // {[2*c2][0..3],[2*c2+1][0..3]} are exactly tokens c2*32 + quad*8 + (0..7)
  // = the k-slots of the 16x16x32_f16 B-fragment. No cross-lane traffic.
#define COMPUTE(KB, VB)                                                         \
  {                                                                             \
    f32x4 sacc[2][4] = {{zero, zero, zero, zero}, {zero, zero, zero, zero}};    \
    __builtin_amdgcn_s_setprio(1);                                              \
    _Pragma("unroll") for (int ks = 0; ks < 2; ++ks) {                          \
      _Pragma("unroll") for (int ct = 0; ct < 4; ++ct) {                        \
        const bf16x8 ak = *(const bf16x8*)(&Kls[KB][(ct * 16 + l15) * 64 +      \
            (((ks * 4 + quad) ^ (l15 & 7)) << 3)]);                             \
        sacc[0][ct] = mfma16(ak, bq[0][ks], sacc[0][ct]);                       \
        sacc[1][ct] = mfma16(ak, bq[1][ks], sacc[1][ct]);                       \
      }                                                                         \
    }                                                                           \
    __builtin_amdgcn_s_setprio(0);                                              \
    f16x8 pf[2][2];                                                             \
    _Pragma("unroll") for (int s = 0; s < 2; ++s)                               \
      _Pragma("unroll") for (int c2 = 0; c2 < 2; ++c2) {                        \
        _Pragma("unroll") for (int r = 0; r < 4; ++r) {                         \
          pf[s][c2][r]     = (_Float16)exp2f(sacc[s][2 * c2][r]);               \
          pf[s][c2][4 + r] = (_Float16)exp2f(sacc[s][2 * c2 + 1][r]);           \
        }                                                                       \
      }                                                                         \
    __builtin_amdgcn_s_setprio(1);                                              \
    _Pragma("unroll") for (int c2 = 0; c2 < 2; ++c2) {                          \
      _Pragma("unroll") for (int dt = 0; dt < 4; ++dt) {                        \
        const f16x8 av = *(const f16x8*)(&Vls[VB][(dt * 16 + l15) * 64 +        \
            (((c2 * 4 + quad) ^ (l15 & 7)) << 3)]);                             \
        oacc[0][dt] = mfmah32(av, pf[0][c2], oacc[0][dt]);                      \
        oacc[1][dt] = mfmah32(av, pf[1][c2], oacc[1][dt]);                      \
      }                                                                         \
      osum[0] = mfmah32(fones8, pf[0][c2], osum[0]);                            \
      osum[1] = mfmah32(fones8, pf[1][c2], osum[1]);                            \
    }                                                                           \
    __builtin_amdgcn_s_setprio(0);                                              \
  }

  // PHASE(kt): vmcnt(WN) [own K(kt),V(kt) loads retired; K(kt+1) in flight]
  // -> barrier [ALL waves' kt loads landed] -> stage V(kt+1) then K(kt+2)
  // (V first so the retirement queue stays [V(kt+1), K(kt+2)] oldest-first)
  // -> compute. V's dest buffer (kt+1)&1 was last read in COMPUTE(kt-1),
  // finished by every wave before this barrier; K's dest (kt+2)%3 likewise.
#define PHASE(KT, KB, VB, VSB, KSB, WN, DV, DK)                                 \
  asm volatile("s_waitcnt vmcnt(" #WN ")" ::: "memory");                        \
  __builtin_amdgcn_s_barrier();                                                 \
  asm volatile("" ::: "memory");                                                \
  if (DV) STAGE_V((KT) + 1, VSB)                                                \
  if (DK) STAGE_K((KT) + 2, KSB)                                                \
  COMPUTE(KB, VB)

  // prologue: V0, K0, K1 (queue oldest-first: V0,K0,K1 -> PHASE(0) vmcnt(2))
  STAGE_V(0, 0)
  STAGE_K(0, 0)
  STAGE_K(1, 1)

#pragma unroll 1
  for (int kt = 0; kt < NT - 6; kt += 6) {
    PHASE(kt + 0, 0, 0, 1, 2, 2, 1, 1)
    PHASE(kt + 1, 1, 1, 0, 0, 2, 1, 1)
    PHASE(kt + 2, 2, 0, 1, 1, 2, 1, 1)
    PHASE(kt + 3, 0, 1, 0, 2, 2, 1, 1)
    PHASE(kt + 4, 1, 0, 1, 0, 2, 1, 1)
    PHASE(kt + 5, 2, 1, 0, 1, 2, 1, 1)
  }
  // tail: kt = 30..35 (NT = 36)
  PHASE(30, 0, 0, 1, 2, 2, 1, 1)
  PHASE(31, 1, 1, 0, 0, 2, 1, 1)
  PHASE(32, 2, 0, 1, 1, 2, 1, 1)
  PHASE(33, 0, 1, 0, 2, 2, 1, 1)   // stages V(34), K(35) -- last valid
  PHASE(34, 1, 0, 1, 0, 2, 1, 0)   // stages V(35) only
  PHASE(35, 2, 1, 0, 0, 0, 0, 0)   // drain all

  // ---- epilogue: rinv from ones-MFMA (all regs equal), normalize, store ----
  const int b = bh >> 4, h = bh & 15;
#pragma unroll
  for (int s = 0; s < 2; ++s) {
    const float rinv = 1.0f / osum[s][0];
    __bf16* Op = Om + ((size_t)b * Nc + qbase + s * 16 + l15) * Ec + h * 64 + quad * 4;
#pragma unroll
    for (int dt = 0; dt < 4; ++dt) {
      bf16x4 o;
#pragma unroll
      for (int r = 0; r < 4; ++r) o[r] = (__bf16)(oacc[s][dt][r] * rinv);
      *(bf16x4*)(Op + dt * 16) = o;
    }
  }
#undef STAGE_K
#undef STAGE_V
#undef COMPUTE
#undef PHASE
}

// ---------------------------------------------------------------------------
extern "C" void kernel_launch(void* const* d_in, const int* in_sizes, int n_in,
                              void* d_out, int out_size, void* d_ws, size_t ws_size,
                              hipStream_t stream) {
  const float* q  = (const float*)d_in[0];
  const float* k  = (const float*)d_in[1];
  const float* v  = (const float*)d_in[2];
  const float* Wq = (const float*)d_in[3];
  const float* bq = (const float*)d_in[4];
  const float* Wk = (const float*)d_in[5];
  const float* bk = (const float*)d_in[6];
  const float* Wv = (const float*)d_in[7];
  const float* bv = (const float*)d_in[8];
  const float* Wo = (const float*)d_in[9];
  const float* bo = (const float*)d_in[10];
  float* out = (float*)d_out;

  const size_t EE = (size_t)Ec * Ec;          // 1 M elems
  const size_t BNE = (size_t)BNc * Ec;        // 9.4 M elems

  // workspace carve (~102 MB with aliasing). qb and kb MUST be adjacent:
  // gemm_qk indexes A as qb + proj*BNE.
  char* w = (char*)d_ws;
  __bf16* Wqkb = (__bf16*)w; w += 2 * EE * 2;  // W_q rows | W_k rows (2048x1024)
  __bf16* Wvb  = (__bf16*)w; w += EE * 2;
  __bf16* Wob  = (__bf16*)w; w += EE * 2;
  __bf16* qb   = (__bf16*)w; w += BNE * 2;
  __bf16* kb   = (__bf16*)w; w += BNE * 2;    // == qb + BNE
  __bf16* vb   = (__bf16*)w; w += BNE * 2;
  __bf16* Qhp  = (__bf16*)w; w += BNE * 2;
  __bf16* Khp  = (__bf16*)w; w += BNE * 2;    // token-permuted + d-swizzled
  _Float16* Vtp = (_Float16*)kb;  // kb dead after gemm_qk; gemm_v writes here
  __bf16* Omp = qb;               // qb dead after gemm_qk; attn writes here

  const dim3 blk(256);
  const dim3 gCvtW(EE / 8 / 256);     // 512
  const dim3 gCvtA(BNE / 8 / 256);    // 4608
  const dim3 gQK(16 * (BNc / 128));   // 1152
  const dim3 gG(8 * (BNc / 128));     // 576
  const dim3 gAttn(Bc * Hc, Nc / TQ); // (64, 18)

  cvt_bf16<<<gCvtW, blk, 0, stream>>>(Wq, Wqkb, (int)EE);
  cvt_bf16<<<gCvtW, blk, 0, stream>>>(Wk, Wqkb + EE, (int)EE);
  cvt_bf16<<<gCvtW, blk, 0, stream>>>(Wv, Wvb, (int)EE);
  cvt_bf16<<<gCvtW, blk, 0, stream>>>(Wo, Wob, (int)EE);
  cvt_bf16<<<gCvtA, blk, 0, stream>>>(q, qb, (int)BNE);
  cvt_bf16<<<gCvtA, blk, 0, stream>>>(k, kb, (int)BNE);
  cvt_bf16<<<gCvtA, blk, 0, stream>>>(v, vb, (int)BNE);

  const float qscale = 0.125f * 1.44269504088896340736f;  // 1/sqrt(64) * log2(e)

  gemm_qk<<<gQK, blk, 0, stream>>>(qb, Wqkb, bq, bk, Qhp, Khp, qscale);
  gemm_v<<<gG, blk, 0, stream>>>(vb, Wvb, bv, Vtp);
  attn<<<gAttn, blk, 0, stream>>>(Qhp, Khp, Vtp, Omp);
  gemm_out<<<gG, blk, 0, stream>>>(Omp, Wob, bo, out);
}

// Round 7
// 448.204 us; speedup vs baseline: 1.1335x; 1.0815x over previous
//
#include <hip/hip_runtime.h>
#include <cstdint>
#include <cstddef>

// ---------------------------------------------------------------------------
// CrossAttention2D: out = softmax((rope(XqWq^T) rope(XkWk^T)^T)/8) (XvWv^T) Wo^T
// B=4, N=48*48=2304, E=1024, H=16, D=64. bf16 MFMA, fp32 accum.
// R11: (1) attn is now LDS-free and barrier-free: gemm_qk/gemm_v write K/V
//     in MFMA-fragment order ([bh][kt][frag 0..7][lane 0..63][8 elems], 1KB
//     per fragment), so attn loads operands with coalesced
//     global_load_dwordx4 straight to registers. K/V per (b,h) is 2x295KB =
//     L2-resident and re-read by 18 q-blocks; staging was overhead
//     (cf. guide Common-mistake #7 / m169). Token permutation and slot
//     mappings are IDENTICAL to the verified R10 kernel - only storage
//     changed. (2) the 7 cvt_bf16 launches merged into one cvt_all (dest
//     regions are contiguous in the workspace carve).
//     GEMMs: R5 single-buffer structure (verified).
// ---------------------------------------------------------------------------

typedef __bf16 bf16x8 __attribute__((ext_vector_type(8)));
typedef __bf16 bf16x4 __attribute__((ext_vector_type(4)));
typedef _Float16 f16x4 __attribute__((ext_vector_type(4)));
typedef _Float16 f16x8 __attribute__((ext_vector_type(8)));
typedef float f32x4 __attribute__((ext_vector_type(4)));

constexpr int Bc = 4, Hc = 16, Nc = 2304, Ec = 1024, WPc = 48;
constexpr int BNc = Bc * Nc;  // 9216

__device__ __forceinline__ f32x4 mfma16(bf16x8 a, bf16x8 b, f32x4 c) {
  return __builtin_amdgcn_mfma_f32_16x16x32_bf16(a, b, c, 0, 0, 0);
}
__device__ __forceinline__ f32x4 mfmah32(f16x8 a, f16x8 b, f32x4 c) {
  return __builtin_amdgcn_mfma_f32_16x16x32_f16(a, b, c, 0, 0, 0);
}

#define GPTR(p) ((const __attribute__((address_space(1))) void*)(p))
#define LPTR(p) ((__attribute__((address_space(3))) void*)(p))

// ------------------- fp32 -> bf16 convert, all 7 arrays ---------------------
// dst layout (contiguous in ws): [Wq EE][Wk EE][Wv EE][Wo EE][q BNE][k BNE][v BNE]
__global__ __launch_bounds__(256) void cvt_all(
    const float* __restrict__ s0, const float* __restrict__ s1,
    const float* __restrict__ s2, const float* __restrict__ s3,
    const float* __restrict__ s4, const float* __restrict__ s5,
    const float* __restrict__ s6, __bf16* __restrict__ d) {
  const size_t EE = (size_t)Ec * Ec, BNE = (size_t)BNc * Ec;
  const size_t g = ((size_t)blockIdx.x * 256 + threadIdx.x) * 8;
  const float* s;
  size_t off;
  if (g < 4 * EE) {            // EE = 1<<20; boundaries are block-uniform
    const size_t a = g >> 20;
    off = g & (EE - 1);
    s = (a == 0) ? s0 : (a == 1) ? s1 : (a == 2) ? s2 : s3;
  } else {
    const size_t h = g - 4 * EE;
    const size_t a = h / BNE;
    off = h - a * BNE;
    s = (a == 0) ? s4 : (a == 1) ? s5 : s6;
  }
  float4 f0 = *(const float4*)(s + off);
  float4 f1 = *(const float4*)(s + off + 4);
  bf16x8 v;
  v[0] = (__bf16)f0.x; v[1] = (__bf16)f0.y; v[2] = (__bf16)f0.z; v[3] = (__bf16)f0.w;
  v[4] = (__bf16)f1.x; v[5] = (__bf16)f1.y; v[6] = (__bf16)f1.z; v[7] = (__bf16)f1.w;
  *(bf16x8*)(d + g) = v;
}

// ---------------- shared GEMM core: 128x128 tile, BK=32, 4 waves ------------
// R5 structure: single LDS buffer, global_load_lds staging, 2 barriers/K-step.
#define GEMM_CORE(APTR, WPTR, KDIM)                                             \
  __shared__ __align__(16) __bf16 As[128 * 32];                                 \
  __shared__ __align__(16) __bf16 Bs[128 * 32];                                 \
  const int t = threadIdx.x;                                                    \
  const int lane = t & 63, wave = t >> 6;                                       \
  const int wm = wave & 1, wn = wave >> 1;                                      \
  const int quad = lane >> 4, l15 = lane & 15;                                  \
  const int rowInC = lane >> 2, colC = (lane & 3) * 8;                          \
  const __bf16* Ab = (APTR) + (size_t)(tm * 128) * (KDIM);                      \
  const __bf16* Wb = (WPTR) + (size_t)(tn * 128) * (KDIM);                      \
  f32x4 zero = {0.f, 0.f, 0.f, 0.f};                                            \
  f32x4 acc[4][4];                                                              \
  for (int i = 0; i < 4; ++i)                                                   \
    for (int j = 0; j < 4; ++j) acc[i][j] = zero;                               \
  for (int kk = 0; kk < (KDIM); kk += 32) {                                     \
    _Pragma("unroll") for (int tch = 0; tch < 2; ++tch) {                       \
      const int ch = wave * 2 + tch;                                            \
      const int row = ch * 16 + rowInC;                                         \
      __builtin_amdgcn_global_load_lds(GPTR(Ab + (size_t)row * (KDIM) + kk + colC), \
                                       LPTR(As + ch * 512), 16, 0, 0);          \
      __builtin_amdgcn_global_load_lds(GPTR(Wb + (size_t)row * (KDIM) + kk + colC), \
                                       LPTR(Bs + ch * 512), 16, 0, 0);          \
    }                                                                           \
    __syncthreads();                                                            \
    bf16x8 af[4], bfg[4];                                                       \
    _Pragma("unroll") for (int i = 0; i < 4; ++i)                               \
        af[i] = *(const bf16x8*)(As + (wm * 64 + i * 16 + l15) * 32 + quad * 8);\
    _Pragma("unroll") for (int j = 0; j < 4; ++j)                               \
        bfg[j] = *(const bf16x8*)(Bs + (wn * 64 + j * 16 + l15) * 32 + quad * 8);\
    _Pragma("unroll") for (int i = 0; i < 4; ++i)                               \
      _Pragma("unroll") for (int j = 0; j < 4; ++j)                             \
        acc[i][j] = mfma16(af[i], bfg[j], acc[i][j]);                           \
    __syncthreads();                                                            \
  }                                                                             \
  const int m0 = tm * 128 + wm * 64;                                            \
  const int nb0 = tn * 128 + wn * 64;

// ---------------- GEMM 1: fused Q+K projection + RoPE + head pack -----------
// Col tiles 0..7 -> Q (natural [bh][tok][64] layout); 8..15 -> K written in
// MFMA-fragment order with the verified token bit-permutation
// t64=[hi q1 q0 c r1 r0] -> stored p64=[hi c q1 q0 r1 r0]: for fragment
// (ct,ks), lane l holds K_stored[ct*16+(l&15)][ks*32+(l>>4)*8+j], j=0..7.
// elem = bh_kt_base + ((ct*2+ks)*64 + (dd>>3)*16 + (p64&15))*8 + (dd&7).
__global__ __launch_bounds__(256) void gemm_qk(const __bf16* __restrict__ qkb,
                                               const __bf16* __restrict__ Wqk,
                                               const float* __restrict__ bq,
                                               const float* __restrict__ bk,
                                               __bf16* __restrict__ Qhp,
                                               __bf16* __restrict__ Khp,
                                               float qscale) {
  const int tn = blockIdx.x & 15;   // 16 col tiles over 2048
  const int tm = blockIdx.x >> 4;   // 72 row tiles
  const int proj = tn >> 3;         // 0 = Q, 1 = K (block-uniform)
  const __bf16* Asel = qkb + (size_t)proj * BNc * Ec;
  GEMM_CORE(Asel, Wqk, Ec)

  const int h = (nb0 >> 6) & 15;
  const float* bb = proj ? bk : bq;
  float bj[4];
#pragma unroll
  for (int j = 0; j < 4; ++j) bj[j] = bb[(nb0 + j * 16 + l15) & 1023];
  const float f = exp2f(-(float)l15 * 0.8304820237218406f);
  const int lo3 = l15 & 7, hi8 = l15 >> 3;
#pragma unroll
  for (int i = 0; i < 4; ++i) {
#pragma unroll
    for (int r = 0; r < 4; ++r) {
      const int m = m0 + i * 16 + quad * 4 + r;
      const int b = m / Nc;
      const int ntok = m - b * Nc;
      const int ph = ntok / WPc, pw = ntok - (ntok / WPc) * WPc;
      float sh, ch, sw, cw;
      __sincosf((float)ph * f, &sh, &ch);
      __sincosf((float)pw * f, &sw, &cw);
      const float x0 = acc[i][0][r] + bj[0];
      const float x1 = acc[i][1][r] + bj[1];
      const float x2 = acc[i][2][r] + bj[2];
      const float x3 = acc[i][3][r] + bj[3];
      const float y0 = x0 * ch - x1 * sh;
      const float y1 = x1 * ch + x0 * sh;
      const float y2 = x2 * cw - x3 * sw;
      const float y3 = x3 * cw + x2 * sw;
      if (proj == 0) {
        __bf16* Op = Qhp + ((size_t)(b * Hc + h) * Nc + ntok) * 64;
        Op[l15]      = (__bf16)(y0 * qscale);
        Op[l15 + 16] = (__bf16)(y1 * qscale);
        Op[l15 + 32] = (__bf16)(y2 * qscale);
        Op[l15 + 48] = (__bf16)(y3 * qscale);
      } else {
        const int t64 = ntok & 63;
        const int p64 = (t64 & 35) | ((t64 & 4) << 2) | ((t64 & 24) >> 1);
        __bf16* Kp = Khp + ((size_t)(b * Hc + h) * 36 + (ntok >> 6)) * 4096 +
                     (size_t)((((p64 >> 4) * 2) * 64 + hi8 * 16 + (p64 & 15)) * 8 + lo3);
        Kp[0]   = (__bf16)y0;   // d = l15       (ks=0, quad_f=hi8)
        Kp[256] = (__bf16)y1;   // d = 16 + l15  (ks=0, quad_f=2+hi8)
        Kp[512] = (__bf16)y2;   // d = 32 + l15  (ks=1, quad_f=hi8)
        Kp[768] = (__bf16)y3;   // d = 48 + l15  (ks=1, quad_f=2+hi8)
      }
    }
  }
}

// ---------------- GEMM 2: V projection -> f16 fragment order ----------------
// Natural token order. Fragment (c2,dt): lane l holds
// V^T[dt*16+(l&15)][c2*32+(l>>4)*8+j], j=0..7.
// elem = bh_kt_base + ((c2*4+dt)*64 + ((t64>>3)&3)*16 + (d&15))*8 + (t64&7).
__global__ __launch_bounds__(256) void gemm_v(const __bf16* __restrict__ A,
                                              const __bf16* __restrict__ Wv,
                                              const float* __restrict__ bv,
                                              _Float16* __restrict__ Vt) {
  const int tn = blockIdx.x & 7;
  const int tm = blockIdx.x >> 3;
  GEMM_CORE(A, Wv, Ec)

  const int h = nb0 >> 6;
#pragma unroll
  for (int i = 0; i < 4; ++i) {
    const int m = m0 + i * 16 + quad * 4;
    const int b = m / Nc;
    const int ntok = m - b * Nc;
    const int t64 = ntok & 63;
    const int c2 = t64 >> 5, qf = (t64 >> 3) & 3, jf0 = t64 & 7;  // jf0 in {0,4}
    const size_t vbase = ((size_t)(b * Hc + h) * 36 + (ntok >> 6)) * 4096;
#pragma unroll
    for (int j = 0; j < 4; ++j) {
      const float bi = bv[nb0 + j * 16 + l15];
      f16x4 v;
#pragma unroll
      for (int r = 0; r < 4; ++r) v[r] = (_Float16)(acc[i][j][r] + bi);
      *(f16x4*)(Vt + vbase +
                (size_t)(((c2 * 4 + j) * 64 + qf * 16 + l15) * 8 + jf0)) = v;
    }
  }
}

// ---------------- GEMM 3: output projection, fp32 + bias --------------------
__global__ __launch_bounds__(256) void gemm_out(const __bf16* __restrict__ A,
                                                const __bf16* __restrict__ Wo,
                                                const float* __restrict__ bo,
                                                float* __restrict__ C) {
  const int tn = blockIdx.x & 7;
  const int tm = blockIdx.x >> 3;
  GEMM_CORE(A, Wo, Ec)

#pragma unroll
  for (int j = 0; j < 4; ++j) {
    const int n = nb0 + j * 16 + l15;
    const float bi = bo[n];
#pragma unroll
    for (int i = 0; i < 4; ++i) {
      const int m = m0 + i * 16 + quad * 4;
#pragma unroll
      for (int r = 0; r < 4; ++r) C[(size_t)(m + r) * Ec + n] = acc[i][j][r] + bi;
    }
  }
}

// --------------------------- flash attention (R11) --------------------------
// LDS-free, barrier-free. 4 independent waves x 32 q-rows. Per k-tile each
// wave loads 8 K fragments + 8 V fragments (coalesced dwordx4, L2-resident)
// straight into MFMA operand registers. Compiler manages all waitcnts.
constexpr int TQ = 128, TK = 64, NT = Nc / TK;  // 18 q-tiles, 36 k-tiles

__global__ __launch_bounds__(256) void attn(const __bf16* __restrict__ Qh,
                                            const __bf16* __restrict__ Kf,
                                            const _Float16* __restrict__ Vf,
                                            __bf16* __restrict__ Om) {
  const int bh = blockIdx.x;
  const int t = threadIdx.x, wave = t >> 6, lane = t & 63;
  const int quad = lane >> 4, l15 = lane & 15;
  const int qbase = blockIdx.y * TQ + wave * 32;

  bf16x8 bq[2][2];
#pragma unroll
  for (int s = 0; s < 2; ++s)
#pragma unroll
    for (int ks = 0; ks < 2; ++ks)
      bq[s][ks] = *(const bf16x8*)(Qh + ((size_t)bh * Nc + qbase + s * 16 + l15) * 64 +
                                   ks * 32 + quad * 8);

  const __bf16* Kb = Kf + (size_t)bh * (NT * 4096) + (size_t)lane * 8;
  const _Float16* Vb = Vf + (size_t)bh * (NT * 4096) + (size_t)lane * 8;

  const f32x4 zero = {0.f, 0.f, 0.f, 0.f};
  f32x4 oacc[2][4] = {{zero, zero, zero, zero}, {zero, zero, zero, zero}};
  f32x4 osum[2] = {zero, zero};
  const f16x8 fones8 = {(_Float16)1.f, (_Float16)1.f, (_Float16)1.f, (_Float16)1.f,
                        (_Float16)1.f, (_Float16)1.f, (_Float16)1.f, (_Float16)1.f};

  for (int kt = 0; kt < NT; ++kt) {
    bf16x8 kf[8];
#pragma unroll
    for (int f = 0; f < 8; ++f)
      kf[f] = *(const bf16x8*)(Kb + (size_t)kt * 4096 + f * 512);
    f16x8 vfr[8];
#pragma unroll
    for (int f = 0; f < 8; ++f)
      vfr[f] = *(const f16x8*)(Vb + (size_t)kt * 4096 + f * 512);

    // QK^T: fragment (ct,ks) = kf[ct*2+ks]. sacc reg layout identical to R10.
    f32x4 sacc[2][4] = {{zero, zero, zero, zero}, {zero, zero, zero, zero}};
    __builtin_amdgcn_s_setprio(1);
#pragma unroll
    for (int ks = 0; ks < 2; ++ks)
#pragma unroll
      for (int ct = 0; ct < 4; ++ct) {
        sacc[0][ct] = mfma16(kf[ct * 2 + ks], bq[0][ks], sacc[0][ct]);
        sacc[1][ct] = mfma16(kf[ct * 2 + ks], bq[1][ks], sacc[1][ct]);
      }
    __builtin_amdgcn_s_setprio(0);

    // P = exp2(S); K-side token permutation makes pf[s][c2][j] the P value
    // for actual token c2*32 + quad*8 + j (verified mapping from R10).
    f16x8 pf[2][2];
#pragma unroll
    for (int s = 0; s < 2; ++s)
#pragma unroll
      for (int c2 = 0; c2 < 2; ++c2) {
#pragma unroll
        for (int r = 0; r < 4; ++r) {
          pf[s][c2][r]     = (_Float16)exp2f(sacc[s][2 * c2][r]);
          pf[s][c2][4 + r] = (_Float16)exp2f(sacc[s][2 * c2 + 1][r]);
        }
      }

    // PV: fragment (c2,dt) = vfr[c2*4+dt]; row-sums via ones-MFMA.
    __builtin_amdgcn_s_setprio(1);
#pragma unroll
    for (int c2 = 0; c2 < 2; ++c2) {
#pragma unroll
      for (int dt = 0; dt < 4; ++dt) {
        oacc[0][dt] = mfmah32(vfr[c2 * 4 + dt], pf[0][c2], oacc[0][dt]);
        oacc[1][dt] = mfmah32(vfr[c2 * 4 + dt], pf[1][c2], oacc[1][dt]);
      }
      osum[0] = mfmah32(fones8, pf[0][c2], osum[0]);
      osum[1] = mfmah32(fones8, pf[1][c2], osum[1]);
    }
    __builtin_amdgcn_s_setprio(0);
  }

  // ---- epilogue: rinv from ones-MFMA (all regs equal), normalize, store ----
  const int b = bh >> 4, h = bh & 15;
#pragma unroll
  for (int s = 0; s < 2; ++s) {
    const float rinv = 1.0f / osum[s][0];
    __bf16* Op = Om + ((size_t)b * Nc + qbase + s * 16 + l15) * Ec + h * 64 + quad * 4;
#pragma unroll
    for (int dt = 0; dt < 4; ++dt) {
      bf16x4 o;
#pragma unroll
      for (int r = 0; r < 4; ++r) o[r] = (__bf16)(oacc[s][dt][r] * rinv);
      *(bf16x4*)(Op + dt * 16) = o;
    }
  }
}

// ---------------------------------------------------------------------------
extern "C" void kernel_launch(void* const* d_in, const int* in_sizes, int n_in,
                              void* d_out, int out_size, void* d_ws, size_t ws_size,
                              hipStream_t stream) {
  const float* q  = (const float*)d_in[0];
  const float* k  = (const float*)d_in[1];
  const float* v  = (const float*)d_in[2];
  const float* Wq = (const float*)d_in[3];
  const float* bq = (const float*)d_in[4];
  const float* Wk = (const float*)d_in[5];
  const float* bk = (const float*)d_in[6];
  const float* Wv = (const float*)d_in[7];
  const float* bv = (const float*)d_in[8];
  const float* Wo = (const float*)d_in[9];
  const float* bo = (const float*)d_in[10];
  float* out = (float*)d_out;

  const size_t EE = (size_t)Ec * Ec;          // 1 M elems
  const size_t BNE = (size_t)BNc * Ec;        // 9.4 M elems

  // workspace carve (~102 MB with aliasing). The first 4EE+3BNE bf16 elems
  // form one contiguous cvt_all destination: [Wq|Wk|Wv|Wo|q|k|v].
  char* w = (char*)d_ws;
  __bf16* Wqkb = (__bf16*)w; w += 2 * EE * 2;  // W_q rows | W_k rows (2048x1024)
  __bf16* Wvb  = (__bf16*)w; w += EE * 2;
  __bf16* Wob  = (__bf16*)w; w += EE * 2;
  __bf16* qb   = (__bf16*)w; w += BNE * 2;
  __bf16* kb   = (__bf16*)w; w += BNE * 2;    // == qb + BNE
  __bf16* vb   = (__bf16*)w; w += BNE * 2;
  __bf16* Qhp  = (__bf16*)w; w += BNE * 2;
  __bf16* Khp  = (__bf16*)w; w += BNE * 2;    // K fragment-packed (36*4096/bh)
  _Float16* Vtp = (_Float16*)kb;  // kb dead after gemm_qk; gemm_v writes here
  __bf16* Omp = qb;               // qb dead after gemm_qk; attn writes here

  const dim3 blk(256);
  const dim3 gCvt((4 * EE + 3 * BNE) / 8 / 256);  // 15872
  const dim3 gQK(16 * (BNc / 128));   // 1152
  const dim3 gG(8 * (BNc / 128));     // 576
  const dim3 gAttn(Bc * Hc, Nc / TQ); // (64, 18)

  cvt_all<<<gCvt, blk, 0, stream>>>(Wq, Wk, Wv, Wo, q, k, v, Wqkb);

  const float qscale = 0.125f * 1.44269504088896340736f;  // 1/sqrt(64) * log2(e)

  gemm_qk<<<gQK, blk, 0, stream>>>(qb, Wqkb, bq, bk, Qhp, Khp, qscale);
  gemm_v<<<gG, blk, 0, stream>>>(vb, Wvb, bv, Vtp);
  attn<<<gAttn, blk, 0, stream>>>(Qhp, Khp, Vtp, Omp);
  gemm_out<<<gG, blk, 0, stream>>>(Omp, Wob, bo, out);
}

// Round 8
// 423.164 us; speedup vs baseline: 1.2006x; 1.0592x over previous
//
#include <hip/hip_runtime.h>
#include <cstdint>
#include <cstddef>

// ---------------------------------------------------------------------------
// CrossAttention2D: out = softmax((rope(XqWq^T) rope(XkWk^T)^T)/8) (XvWv^T) Wo^T
// B=4, N=48*48=2304, E=1024, H=16, D=64. bf16 MFMA, fp32 accum.
// R12: attn keeps R11's LDS-free/barrier-free fragment-direct structure
//     (448us total, verified) and adds: (1) explicit register double-buffer
//     of the K/V fragments (named kfA/kfB, vfA/vfB per rule #20) so tile
//     kt+1's 16 L2 loads are in flight during tile kt's compute - R11
//     exposed ~200cyc L2 latency per tile (VGPR=88 proved no pipelining);
//     (2) native __builtin_amdgcn_exp2f for the 32 exp/tile/lane VALU chunk.
//     GEMMs + cvt_all identical to R11 (verified).
// ---------------------------------------------------------------------------

typedef __bf16 bf16x8 __attribute__((ext_vector_type(8)));
typedef __bf16 bf16x4 __attribute__((ext_vector_type(4)));
typedef _Float16 f16x4 __attribute__((ext_vector_type(4)));
typedef _Float16 f16x8 __attribute__((ext_vector_type(8)));
typedef float f32x4 __attribute__((ext_vector_type(4)));

constexpr int Bc = 4, Hc = 16, Nc = 2304, Ec = 1024, WPc = 48;
constexpr int BNc = Bc * Nc;  // 9216

__device__ __forceinline__ f32x4 mfma16(bf16x8 a, bf16x8 b, f32x4 c) {
  return __builtin_amdgcn_mfma_f32_16x16x32_bf16(a, b, c, 0, 0, 0);
}
__device__ __forceinline__ f32x4 mfmah32(f16x8 a, f16x8 b, f32x4 c) {
  return __builtin_amdgcn_mfma_f32_16x16x32_f16(a, b, c, 0, 0, 0);
}

#if __has_builtin(__builtin_amdgcn_exp2f)
#define EXP2F(x) __builtin_amdgcn_exp2f(x)
#else
#define EXP2F(x) exp2f(x)
#endif

#define GPTR(p) ((const __attribute__((address_space(1))) void*)(p))
#define LPTR(p) ((__attribute__((address_space(3))) void*)(p))

// ------------------- fp32 -> bf16 convert, all 7 arrays ---------------------
// dst layout (contiguous in ws): [Wq EE][Wk EE][Wv EE][Wo EE][q BNE][k BNE][v BNE]
__global__ __launch_bounds__(256) void cvt_all(
    const float* __restrict__ s0, const float* __restrict__ s1,
    const float* __restrict__ s2, const float* __restrict__ s3,
    const float* __restrict__ s4, const float* __restrict__ s5,
    const float* __restrict__ s6, __bf16* __restrict__ d) {
  const size_t EE = (size_t)Ec * Ec, BNE = (size_t)BNc * Ec;
  const size_t g = ((size_t)blockIdx.x * 256 + threadIdx.x) * 8;
  const float* s;
  size_t off;
  if (g < 4 * EE) {            // EE = 1<<20; boundaries are block-uniform
    const size_t a = g >> 20;
    off = g & (EE - 1);
    s = (a == 0) ? s0 : (a == 1) ? s1 : (a == 2) ? s2 : s3;
  } else {
    const size_t h = g - 4 * EE;
    const size_t a = h / BNE;
    off = h - a * BNE;
    s = (a == 0) ? s4 : (a == 1) ? s5 : s6;
  }
  float4 f0 = *(const float4*)(s + off);
  float4 f1 = *(const float4*)(s + off + 4);
  bf16x8 v;
  v[0] = (__bf16)f0.x; v[1] = (__bf16)f0.y; v[2] = (__bf16)f0.z; v[3] = (__bf16)f0.w;
  v[4] = (__bf16)f1.x; v[5] = (__bf16)f1.y; v[6] = (__bf16)f1.z; v[7] = (__bf16)f1.w;
  *(bf16x8*)(d + g) = v;
}

// ---------------- shared GEMM core: 128x128 tile, BK=32, 4 waves ------------
// R5 structure: single LDS buffer, global_load_lds staging, 2 barriers/K-step.
#define GEMM_CORE(APTR, WPTR, KDIM)                                             \
  __shared__ __align__(16) __bf16 As[128 * 32];                                 \
  __shared__ __align__(16) __bf16 Bs[128 * 32];                                 \
  const int t = threadIdx.x;                                                    \
  const int lane = t & 63, wave = t >> 6;                                       \
  const int wm = wave & 1, wn = wave >> 1;                                      \
  const int quad = lane >> 4, l15 = lane & 15;                                  \
  const int rowInC = lane >> 2, colC = (lane & 3) * 8;                          \
  const __bf16* Ab = (APTR) + (size_t)(tm * 128) * (KDIM);                      \
  const __bf16* Wb = (WPTR) + (size_t)(tn * 128) * (KDIM);                      \
  f32x4 zero = {0.f, 0.f, 0.f, 0.f};                                            \
  f32x4 acc[4][4];                                                              \
  for (int i = 0; i < 4; ++i)                                                   \
    for (int j = 0; j < 4; ++j) acc[i][j] = zero;                               \
  for (int kk = 0; kk < (KDIM); kk += 32) {                                     \
    _Pragma("unroll") for (int tch = 0; tch < 2; ++tch) {                       \
      const int ch = wave * 2 + tch;                                            \
      const int row = ch * 16 + rowInC;                                         \
      __builtin_amdgcn_global_load_lds(GPTR(Ab + (size_t)row * (KDIM) + kk + colC), \
                                       LPTR(As + ch * 512), 16, 0, 0);          \
      __builtin_amdgcn_global_load_lds(GPTR(Wb + (size_t)row * (KDIM) + kk + colC), \
                                       LPTR(Bs + ch * 512), 16, 0, 0);          \
    }                                                                           \
    __syncthreads();                                                            \
    bf16x8 af[4], bfg[4];                                                       \
    _Pragma("unroll") for (int i = 0; i < 4; ++i)                               \
        af[i] = *(const bf16x8*)(As + (wm * 64 + i * 16 + l15) * 32 + quad * 8);\
    _Pragma("unroll") for (int j = 0; j < 4; ++j)                               \
        bfg[j] = *(const bf16x8*)(Bs + (wn * 64 + j * 16 + l15) * 32 + quad * 8);\
    _Pragma("unroll") for (int i = 0; i < 4; ++i)                               \
      _Pragma("unroll") for (int j = 0; j < 4; ++j)                             \
        acc[i][j] = mfma16(af[i], bfg[j], acc[i][j]);                           \
    __syncthreads();                                                            \
  }                                                                             \
  const int m0 = tm * 128 + wm * 64;                                            \
  const int nb0 = tn * 128 + wn * 64;

// ---------------- GEMM 1: fused Q+K projection + RoPE + head pack -----------
// Col tiles 0..7 -> Q (natural [bh][tok][64] layout); 8..15 -> K written in
// MFMA-fragment order with the verified token bit-permutation
// t64=[hi q1 q0 c r1 r0] -> stored p64=[hi c q1 q0 r1 r0]: for fragment
// (ct,ks), lane l holds K_stored[ct*16+(l&15)][ks*32+(l>>4)*8+j], j=0..7.
__global__ __launch_bounds__(256) void gemm_qk(const __bf16* __restrict__ qkb,
                                               const __bf16* __restrict__ Wqk,
                                               const float* __restrict__ bq,
                                               const float* __restrict__ bk,
                                               __bf16* __restrict__ Qhp,
                                               __bf16* __restrict__ Khp,
                                               float qscale) {
  const int tn = blockIdx.x & 15;   // 16 col tiles over 2048
  const int tm = blockIdx.x >> 4;   // 72 row tiles
  const int proj = tn >> 3;         // 0 = Q, 1 = K (block-uniform)
  const __bf16* Asel = qkb + (size_t)proj * BNc * Ec;
  GEMM_CORE(Asel, Wqk, Ec)

  const int h = (nb0 >> 6) & 15;
  const float* bb = proj ? bk : bq;
  float bj[4];
#pragma unroll
  for (int j = 0; j < 4; ++j) bj[j] = bb[(nb0 + j * 16 + l15) & 1023];
  const float f = exp2f(-(float)l15 * 0.8304820237218406f);
  const int lo3 = l15 & 7, hi8 = l15 >> 3;
#pragma unroll
  for (int i = 0; i < 4; ++i) {
#pragma unroll
    for (int r = 0; r < 4; ++r) {
      const int m = m0 + i * 16 + quad * 4 + r;
      const int b = m / Nc;
      const int ntok = m - b * Nc;
      const int ph = ntok / WPc, pw = ntok - (ntok / WPc) * WPc;
      float sh, ch, sw, cw;
      __sincosf((float)ph * f, &sh, &ch);
      __sincosf((float)pw * f, &sw, &cw);
      const float x0 = acc[i][0][r] + bj[0];
      const float x1 = acc[i][1][r] + bj[1];
      const float x2 = acc[i][2][r] + bj[2];
      const float x3 = acc[i][3][r] + bj[3];
      const float y0 = x0 * ch - x1 * sh;
      const float y1 = x1 * ch + x0 * sh;
      const float y2 = x2 * cw - x3 * sw;
      const float y3 = x3 * cw + x2 * sw;
      if (proj == 0) {
        __bf16* Op = Qhp + ((size_t)(b * Hc + h) * Nc + ntok) * 64;
        Op[l15]      = (__bf16)(y0 * qscale);
        Op[l15 + 16] = (__bf16)(y1 * qscale);
        Op[l15 + 32] = (__bf16)(y2 * qscale);
        Op[l15 + 48] = (__bf16)(y3 * qscale);
      } else {
        const int t64 = ntok & 63;
        const int p64 = (t64 & 35) | ((t64 & 4) << 2) | ((t64 & 24) >> 1);
        __bf16* Kp = Khp + ((size_t)(b * Hc + h) * 36 + (ntok >> 6)) * 4096 +
                     (size_t)((((p64 >> 4) * 2) * 64 + hi8 * 16 + (p64 & 15)) * 8 + lo3);
        Kp[0]   = (__bf16)y0;   // d = l15       (ks=0, quad_f=hi8)
        Kp[256] = (__bf16)y1;   // d = 16 + l15  (ks=0, quad_f=2+hi8)
        Kp[512] = (__bf16)y2;   // d = 32 + l15  (ks=1, quad_f=hi8)
        Kp[768] = (__bf16)y3;   // d = 48 + l15  (ks=1, quad_f=2+hi8)
      }
    }
  }
}

// ---------------- GEMM 2: V projection -> f16 fragment order ----------------
// Natural token order. Fragment (c2,dt): lane l holds
// V^T[dt*16+(l&15)][c2*32+(l>>4)*8+j], j=0..7.
__global__ __launch_bounds__(256) void gemm_v(const __bf16* __restrict__ A,
                                              const __bf16* __restrict__ Wv,
                                              const float* __restrict__ bv,
                                              _Float16* __restrict__ Vt) {
  const int tn = blockIdx.x & 7;
  const int tm = blockIdx.x >> 3;
  GEMM_CORE(A, Wv, Ec)

  const int h = nb0 >> 6;
#pragma unroll
  for (int i = 0; i < 4; ++i) {
    const int m = m0 + i * 16 + quad * 4;
    const int b = m / Nc;
    const int ntok = m - b * Nc;
    const int t64 = ntok & 63;
    const int c2 = t64 >> 5, qf = (t64 >> 3) & 3, jf0 = t64 & 7;  // jf0 in {0,4}
    const size_t vbase = ((size_t)(b * Hc + h) * 36 + (ntok >> 6)) * 4096;
#pragma unroll
    for (int j = 0; j < 4; ++j) {
      const float bi = bv[nb0 + j * 16 + l15];
      f16x4 v;
#pragma unroll
      for (int r = 0; r < 4; ++r) v[r] = (_Float16)(acc[i][j][r] + bi);
      *(f16x4*)(Vt + vbase +
                (size_t)(((c2 * 4 + j) * 64 + qf * 16 + l15) * 8 + jf0)) = v;
    }
  }
}

// ---------------- GEMM 3: output projection, fp32 + bias --------------------
__global__ __launch_bounds__(256) void gemm_out(const __bf16* __restrict__ A,
                                                const __bf16* __restrict__ Wo,
                                                const float* __restrict__ bo,
                                                float* __restrict__ C) {
  const int tn = blockIdx.x & 7;
  const int tm = blockIdx.x >> 3;
  GEMM_CORE(A, Wo, Ec)

#pragma unroll
  for (int j = 0; j < 4; ++j) {
    const int n = nb0 + j * 16 + l15;
    const float bi = bo[n];
#pragma unroll
    for (int i = 0; i < 4; ++i) {
      const int m = m0 + i * 16 + quad * 4;
#pragma unroll
      for (int r = 0; r < 4; ++r) C[(size_t)(m + r) * Ec + n] = acc[i][j][r] + bi;
    }
  }
}

// --------------------------- flash attention (R12) --------------------------
// LDS-free, barrier-free, register double-buffered. 4 independent waves x 32
// q-rows. Tile kt+1's 16 fragment loads (coalesced dwordx4, L2-resident) are
// issued before tile kt's compute; named A/B buffers keep all indexing static.
constexpr int TQ = 128, TK = 64, NT = Nc / TK;  // 18 q-tiles, 36 k-tiles

__global__ __launch_bounds__(256) void attn(const __bf16* __restrict__ Qh,
                                            const __bf16* __restrict__ Kf,
                                            const _Float16* __restrict__ Vf,
                                            __bf16* __restrict__ Om) {
  const int bh = blockIdx.x;
  const int t = threadIdx.x, wave = t >> 6, lane = t & 63;
  const int quad = lane >> 4, l15 = lane & 15;
  const int qbase = blockIdx.y * TQ + wave * 32;

  bf16x8 bq[2][2];
#pragma unroll
  for (int s = 0; s < 2; ++s)
#pragma unroll
    for (int ks = 0; ks < 2; ++ks)
      bq[s][ks] = *(const bf16x8*)(Qh + ((size_t)bh * Nc + qbase + s * 16 + l15) * 64 +
                                   ks * 32 + quad * 8);

  const __bf16* Kb = Kf + (size_t)bh * (NT * 4096) + (size_t)lane * 8;
  const _Float16* Vb = Vf + (size_t)bh * (NT * 4096) + (size_t)lane * 8;

  const f32x4 zero = {0.f, 0.f, 0.f, 0.f};
  f32x4 oacc[2][4] = {{zero, zero, zero, zero}, {zero, zero, zero, zero}};
  f32x4 osum[2] = {zero, zero};
  const f16x8 fones8 = {(_Float16)1.f, (_Float16)1.f, (_Float16)1.f, (_Float16)1.f,
                        (_Float16)1.f, (_Float16)1.f, (_Float16)1.f, (_Float16)1.f};

#define LOADKV(KF, VF, KT)                                                      \
  {                                                                             \
    _Pragma("unroll") for (int f = 0; f < 8; ++f)                               \
      KF[f] = *(const bf16x8*)(Kb + (size_t)(KT) * 4096 + f * 512);             \
    _Pragma("unroll") for (int f = 0; f < 8; ++f)                               \
      VF[f] = *(const f16x8*)(Vb + (size_t)(KT) * 4096 + f * 512);              \
  }

  // QK^T fragment (ct,ks) = KF[ct*2+ks]; sacc layout as in R10/R11.
  // PV fragment (c2,dt) = VF[c2*4+dt]; row-sums via ones-MFMA.
#define COMPUTE(KF, VF)                                                         \
  {                                                                             \
    f32x4 sacc[2][4] = {{zero, zero, zero, zero}, {zero, zero, zero, zero}};    \
    __builtin_amdgcn_s_setprio(1);                                              \
    _Pragma("unroll") for (int ks = 0; ks < 2; ++ks)                            \
      _Pragma("unroll") for (int ct = 0; ct < 4; ++ct) {                        \
        sacc[0][ct] = mfma16(KF[ct * 2 + ks], bq[0][ks], sacc[0][ct]);          \
        sacc[1][ct] = mfma16(KF[ct * 2 + ks], bq[1][ks], sacc[1][ct]);          \
      }                                                                         \
    __builtin_amdgcn_s_setprio(0);                                              \
    f16x8 pf[2][2];                                                             \
    _Pragma("unroll") for (int s = 0; s < 2; ++s)                               \
      _Pragma("unroll") for (int c2 = 0; c2 < 2; ++c2) {                        \
        _Pragma("unroll") for (int r = 0; r < 4; ++r) {                         \
          pf[s][c2][r]     = (_Float16)EXP2F(sacc[s][2 * c2][r]);               \
          pf[s][c2][4 + r] = (_Float16)EXP2F(sacc[s][2 * c2 + 1][r]);           \
        }                                                                       \
      }                                                                         \
    __builtin_amdgcn_s_setprio(1);                                              \
    _Pragma("unroll") for (int c2 = 0; c2 < 2; ++c2) {                          \
      _Pragma("unroll") for (int dt = 0; dt < 4; ++dt) {                        \
        oacc[0][dt] = mfmah32(VF[c2 * 4 + dt], pf[0][c2], oacc[0][dt]);         \
        oacc[1][dt] = mfmah32(VF[c2 * 4 + dt], pf[1][c2], oacc[1][dt]);         \
      }                                                                         \
      osum[0] = mfmah32(fones8, pf[0][c2], osum[0]);                            \
      osum[1] = mfmah32(fones8, pf[1][c2], osum[1]);                            \
    }                                                                           \
    __builtin_amdgcn_s_setprio(0);                                              \
  }

  bf16x8 kfA[8], kfB[8];
  f16x8 vfA[8], vfB[8];
  LOADKV(kfA, vfA, 0)

#pragma unroll 1
  for (int kt = 0; kt < NT; kt += 2) {   // NT = 36, even
    LOADKV(kfB, vfB, kt + 1)
    COMPUTE(kfA, vfA)
    if (kt + 2 < NT) LOADKV(kfA, vfA, kt + 2)
    COMPUTE(kfB, vfB)
  }

  // ---- epilogue: rinv from ones-MFMA (all regs equal), normalize, store ----
  const int b = bh >> 4, h = bh & 15;
#pragma unroll
  for (int s = 0; s < 2; ++s) {
    const float rinv = 1.0f / osum[s][0];
    __bf16* Op = Om + ((size_t)b * Nc + qbase + s * 16 + l15) * Ec + h * 64 + quad * 4;
#pragma unroll
    for (int dt = 0; dt < 4; ++dt) {
      bf16x4 o;
#pragma unroll
      for (int r = 0; r < 4; ++r) o[r] = (__bf16)(oacc[s][dt][r] * rinv);
      *(bf16x4*)(Op + dt * 16) = o;
    }
  }
#undef LOADKV
#undef COMPUTE
}

// ---------------------------------------------------------------------------
extern "C" void kernel_launch(void* const* d_in, const int* in_sizes, int n_in,
                              void* d_out, int out_size, void* d_ws, size_t ws_size,
                              hipStream_t stream) {
  const float* q  = (const float*)d_in[0];
  const float* k  = (const float*)d_in[1];
  const float* v  = (const float*)d_in[2];
  const float* Wq = (const float*)d_in[3];
  const float* bq = (const float*)d_in[4];
  const float* Wk = (const float*)d_in[5];
  const float* bk = (const float*)d_in[6];
  const float* Wv = (const float*)d_in[7];
  const float* bv = (const float*)d_in[8];
  const float* Wo = (const float*)d_in[9];
  const float* bo = (const float*)d_in[10];
  float* out = (float*)d_out;

  const size_t EE = (size_t)Ec * Ec;          // 1 M elems
  const size_t BNE = (size_t)BNc * Ec;        // 9.4 M elems

  // workspace carve (~102 MB with aliasing). The first 4EE+3BNE bf16 elems
  // form one contiguous cvt_all destination: [Wq|Wk|Wv|Wo|q|k|v].
  char* w = (char*)d_ws;
  __bf16* Wqkb = (__bf16*)w; w += 2 * EE * 2;  // W_q rows | W_k rows (2048x1024)
  __bf16* Wvb  = (__bf16*)w; w += EE * 2;
  __bf16* Wob  = (__bf16*)w; w += EE * 2;
  __bf16* qb   = (__bf16*)w; w += BNE * 2;
  __bf16* kb   = (__bf16*)w; w += BNE * 2;    // == qb + BNE
  __bf16* vb   = (__bf16*)w; w += BNE * 2;
  __bf16* Qhp  = (__bf16*)w; w += BNE * 2;
  __bf16* Khp  = (__bf16*)w; w += BNE * 2;    // K fragment-packed (36*4096/bh)
  _Float16* Vtp = (_Float16*)kb;  // kb dead after gemm_qk; gemm_v writes here
  __bf16* Omp = qb;               // qb dead after gemm_qk; attn writes here

  const dim3 blk(256);
  const dim3 gCvt((4 * EE + 3 * BNE) / 8 / 256);  // 15872
  const dim3 gQK(16 * (BNc / 128));   // 1152
  const dim3 gG(8 * (BNc / 128));     // 576
  const dim3 gAttn(Bc * Hc, Nc / TQ); // (64, 18)

  cvt_all<<<gCvt, blk, 0, stream>>>(Wq, Wk, Wv, Wo, q, k, v, Wqkb);

  const float qscale = 0.125f * 1.44269504088896340736f;  // 1/sqrt(64) * log2(e)

  gemm_qk<<<gQK, blk, 0, stream>>>(qb, Wqkb, bq, bk, Qhp, Khp, qscale);
  gemm_v<<<gG, blk, 0, stream>>>(vb, Wvb, bv, Vtp);
  attn<<<gAttn, blk, 0, stream>>>(Qhp, Khp, Vtp, Omp);
  gemm_out<<<gG, blk, 0, stream>>>(Omp, Wob, bo, out);
}